// Round 1
// baseline (400.556 us; speedup 1.0000x reference)
//
#include <hip/hip_runtime.h>
#include <hip/hip_bf16.h>

// out = blur(img[0]/max)*max == blur(img[0]) (linear blur; normalization cancels).
// Separable 25-tap Gaussian, sigma=4, replicate padding, C=3, H=W=4096, fp32.
//
// R1 change: both passes rewritten from sliding-window/gather form to
// streaming accumulator (scatter) form. Eliminates the 25-deep float2 window
// (~50 VGPR + up to 768 shift-movs/thread) in the vertical pass and the
// v[48] buffer in the horizontal pass. Per-output FP add order is unchanged
// (ascending k), so results are bit-identical to the 394.4us baseline.

#define IMG_W 4096
#define IMG_H 4096
#define N_CH  3
#define HALF  12
#define KSZ   25

#define TILE_W 96                 // output tile width
#define TILE_H 64                 // output tile height
#define COLS   (TILE_W + 2*HALF)  // 120 intermediate columns
#define LDS_STRIDE 124            // 16B-aligned rows; 124%32=28 spreads banks
#define GRP_ROWS 16               // output rows per vertical task
#define N_GRP    4                // 4 row groups -> 64 rows
#define VROWS (GRP_ROWS + 2*HALF) // 40 input rows per vertical task
#define VCOLS2 (COLS/2)           // 60 float2 columns
#define HCHUNK 24                 // output px per horizontal task (96/4)
#define HREAD  (HCHUNK + 2*HALF)  // 48 floats = 12 x b128

// NOTE: no min-waves hint. A previous __launch_bounds__(256,5) forced VGPR=48,
// spilling ~40 floats/thread to scratch -> 1.6x slower. Let the allocator
// have what it needs; accumulator form keeps live sets small anyway.

__device__ __constant__ float kW[KSZ] = {
    0.00110988f, 0.00227883f, 0.00438965f, 0.00794860f, 0.01352109f,
    0.02160664f, 0.03243540f, 0.04574124f, 0.06059730f, 0.07541456f,
    0.08816855f, 0.09683420f, 0.09990806f, 0.09683420f, 0.08816855f,
    0.07541456f, 0.06059730f, 0.04574124f, 0.03243540f, 0.02160664f,
    0.01352109f, 0.00794860f, 0.00438965f, 0.00227883f, 0.00110988f
};

__global__ __launch_bounds__(256)
void gauss_blur_fused(const float* __restrict__ img, float* __restrict__ out)
{
    __shared__ float inter[TILE_H * LDS_STRIDE]; // 64*124*4 = 31744 B

    const int tid = threadIdx.x;
    const int x0  = blockIdx.x * TILE_W;
    const int y0  = blockIdx.y * TILE_H;
    const int c   = blockIdx.z;

    const float* __restrict__ src = img + (size_t)c * IMG_W * IMG_H;
    float* __restrict__ dst       = out + (size_t)c * IMG_W * IMG_H;

    // ---------------- vertical pass: float2 columns, streaming accumulators.
    // For input row j (0..39), it contributes kW[j-i] to outputs i in
    // [j-24, j] n [0,15].  Per output the adds still arrive k=0..24 ascending.
    if (tid < VCOLS2 * N_GRP) {          // 240 active
        const int c2 = tid % VCOLS2;     // 0..59
        const int g  = tid / VCOLS2;     // 0..3
        const int gx = x0 - HALF + 2 * c2;       // even; pairs never straddle an edge
        const int ybase = y0 + g * GRP_ROWS - HALF;
        const int ldscol = 2 * c2;

        float2 acc[GRP_ROWS];            // 16 float2 accumulators (32 VGPR)
        #pragma unroll
        for (int i = 0; i < GRP_ROWS; ++i) { acc[i].x = 0.f; acc[i].y = 0.f; }

        if (gx >= 0 && gx <= IMG_W - 2) {
            if (ybase >= 0 && ybase + VROWS <= IMG_H) {
                // interior fast path
                const float* p = src + (size_t)ybase * IMG_W + gx;
                #pragma unroll
                for (int j = 0; j < VROWS; ++j) {
                    const float2 wv = *(const float2*)(p + (size_t)j * IMG_W);
                    const int ilo = (j - (KSZ - 1)) < 0 ? 0 : (j - (KSZ - 1));
                    const int ihi = j < (GRP_ROWS - 1) ? j : (GRP_ROWS - 1);
                    #pragma unroll
                    for (int i = ilo; i <= ihi; ++i) {
                        const float kk = kW[j - i];
                        acc[i].x += kk * wv.x;
                        acc[i].y += kk * wv.y;
                    }
                }
            } else {
                // y-edge: clamp rows
                #pragma unroll
                for (int j = 0; j < VROWS; ++j) {
                    int gy = ybase + j;
                    gy = gy < 0 ? 0 : (gy > IMG_H - 1 ? IMG_H - 1 : gy);
                    const float2 wv = *(const float2*)(src + (size_t)gy * IMG_W + gx);
                    const int ilo = (j - (KSZ - 1)) < 0 ? 0 : (j - (KSZ - 1));
                    const int ihi = j < (GRP_ROWS - 1) ? j : (GRP_ROWS - 1);
                    #pragma unroll
                    for (int i = ilo; i <= ihi; ++i) {
                        const float kk = kW[j - i];
                        acc[i].x += kk * wv.x;
                        acc[i].y += kk * wv.y;
                    }
                }
            }
        } else {
            // x-edge: whole pair clamps to the same edge column (gx always even)
            const int gc = gx < 0 ? 0 : IMG_W - 1;
            #pragma unroll
            for (int j = 0; j < VROWS; ++j) {
                int gy = ybase + j;
                gy = gy < 0 ? 0 : (gy > IMG_H - 1 ? IMG_H - 1 : gy);
                const float v = src[(size_t)gy * IMG_W + gc];
                const int ilo = (j - (KSZ - 1)) < 0 ? 0 : (j - (KSZ - 1));
                const int ihi = j < (GRP_ROWS - 1) ? j : (GRP_ROWS - 1);
                #pragma unroll
                for (int i = ilo; i <= ihi; ++i) {
                    const float kk = kW[j - i];
                    acc[i].x += kk * v;
                    acc[i].y += kk * v;
                }
            }
        }

        #pragma unroll
        for (int i = 0; i < GRP_ROWS; ++i)
            *(float2*)&inter[(g * GRP_ROWS + i) * LDS_STRIDE + ldscol] = acc[i];
    }
    __syncthreads();

    // ---------------- horizontal pass: b128 LDS reads, streaming accumulators
    {
        const int row   = tid >> 2;        // 0..63
        const int chunk = tid & 3;         // 0..3
        const int xl    = chunk * HCHUNK;  // 0,24,48,72 -> 16B aligned

        float acc[HCHUNK];                 // 24 accumulators
        #pragma unroll
        for (int j = 0; j < HCHUNK; ++j) acc[j] = 0.f;

        const float4* lp = (const float4*)&inter[row * LDS_STRIDE + xl];
        #pragma unroll
        for (int m4 = 0; m4 < HREAD / 4; ++m4) {   // 12 x ds_read_b128
            const float4 t = lp[m4];
            #pragma unroll
            for (int e = 0; e < 4; ++e) {
                const int m = 4 * m4 + e;
                const float wv = (e == 0) ? t.x : (e == 1) ? t.y : (e == 2) ? t.z : t.w;
                const int jlo = (m - (KSZ - 1)) < 0 ? 0 : (m - (KSZ - 1));
                const int jhi = m < (HCHUNK - 1) ? m : (HCHUNK - 1);
                #pragma unroll
                for (int j = jlo; j <= jhi; ++j)
                    acc[j] += kW[m - j] * wv;
            }
        }

        const size_t rowbase = (size_t)(y0 + row) * IMG_W;
        const int gx0 = x0 + xl;
        #pragma unroll
        for (int j4 = 0; j4 < HCHUNK / 4; ++j4) {
            float4 o;
            o.x = acc[4 * j4 + 0]; o.y = acc[4 * j4 + 1];
            o.z = acc[4 * j4 + 2]; o.w = acc[4 * j4 + 3];
            const int gx = gx0 + 4 * j4;            // multiple of 4
            if (gx < IMG_W)
                *(float4*)&dst[rowbase + gx] = o;
        }
    }
}

extern "C" void kernel_launch(void* const* d_in, const int* in_sizes, int n_in,
                              void* d_out, int out_size, void* d_ws, size_t ws_size,
                              hipStream_t stream)
{
    const float* img = (const float*)d_in[0];
    float* out = (float*)d_out;

    dim3 grid((IMG_W + TILE_W - 1) / TILE_W,  // 43
              IMG_H / TILE_H,                 // 64
              N_CH);                          // 3
    dim3 block(256);
    gauss_blur_fused<<<grid, block, 0, stream>>>(img, out);
}

// Round 4
// 397.849 us; speedup vs baseline: 1.0068x; 1.0068x over previous
//
#include <hip/hip_runtime.h>
#include <hip/hip_bf16.h>

// out = blur(img[0]/max)*max == blur(img[0]) (linear blur; normalization cancels).
// Separable 25-tap Gaussian, sigma=4, replicate padding, C=3, H=W=4096, fp32.
//
// R2-R4 change (resubmit x2 — R2/R3 never ran, infra failures): halve TILE_H
// 64->32 (LDS 31744B -> 15872B). Residency cap goes from 5 blocks/CU (20
// waves, 62.5%) to 8 blocks/CU (32 waves, 100%) as long as VGPR stays <= 64.
// R1 counters showed latency/occupancy-bound: VALUBusy 28.6%, HBM 35% of
// peak, Occupancy 42%. Vertical accumulator set also halves (16 float2 ->
// 8 float2 = 16 VGPR), protecting the VGPR<=64 cap.

#define IMG_W 4096
#define IMG_H 4096
#define N_CH  3
#define HALF  12
#define KSZ   25

#define TILE_W 96                 // output tile width
#define TILE_H 32                 // output tile height (was 64)
#define COLS   (TILE_W + 2*HALF)  // 120 intermediate columns
#define LDS_STRIDE 124            // 16B-aligned rows; 124%32=28 spreads banks
#define GRP_ROWS 8                // output rows per vertical task (was 16)
#define N_GRP    4                // 4 row groups -> 32 rows
#define VROWS (GRP_ROWS + 2*HALF) // 32 input rows per vertical task
#define VCOLS2 (COLS/2)           // 60 float2 columns
#define HCHUNK 12                 // output px per horizontal task (96/8)
#define HREAD  (HCHUNK + 2*HALF)  // 36 floats = 9 x b128

// NOTE: no min-waves hint in __launch_bounds__. A previous (256,5) hint
// forced VGPR=48 and spilled ~40 floats/thread to scratch (1.6x slower).

__device__ __constant__ float kW[KSZ] = {
    0.00110988f, 0.00227883f, 0.00438965f, 0.00794860f, 0.01352109f,
    0.02160664f, 0.03243540f, 0.04574124f, 0.06059730f, 0.07541456f,
    0.08816855f, 0.09683420f, 0.09990806f, 0.09683420f, 0.08816855f,
    0.07541456f, 0.06059730f, 0.04574124f, 0.03243540f, 0.02160664f,
    0.01352109f, 0.00794860f, 0.00438965f, 0.00227883f, 0.00110988f
};

__global__ __launch_bounds__(256)
void gauss_blur_fused(const float* __restrict__ img, float* __restrict__ out)
{
    __shared__ float inter[TILE_H * LDS_STRIDE]; // 32*124*4 = 15872 B

    const int tid = threadIdx.x;
    const int x0  = blockIdx.x * TILE_W;
    const int y0  = blockIdx.y * TILE_H;
    const int c   = blockIdx.z;

    const float* __restrict__ src = img + (size_t)c * IMG_W * IMG_H;
    float* __restrict__ dst       = out + (size_t)c * IMG_W * IMG_H;

    // ---------------- vertical pass: float2 columns, streaming accumulators.
    // Input row j (0..31) contributes kW[j-i] to outputs i in [j-24, j] n [0,7].
    // Per output the adds still arrive k=0..24 ascending (bit-identical order).
    if (tid < VCOLS2 * N_GRP) {          // 240 active
        const int c2 = tid % VCOLS2;     // 0..59
        const int g  = tid / VCOLS2;     // 0..3
        const int gx = x0 - HALF + 2 * c2;       // even; pairs never straddle an edge
        const int ybase = y0 + g * GRP_ROWS - HALF;
        const int ldscol = 2 * c2;

        float2 acc[GRP_ROWS];            // 8 float2 accumulators (16 VGPR)
        #pragma unroll
        for (int i = 0; i < GRP_ROWS; ++i) { acc[i].x = 0.f; acc[i].y = 0.f; }

        if (gx >= 0 && gx <= IMG_W - 2) {
            if (ybase >= 0 && ybase + VROWS <= IMG_H) {
                // interior fast path
                const float* p = src + (size_t)ybase * IMG_W + gx;
                #pragma unroll
                for (int j = 0; j < VROWS; ++j) {
                    const float2 wv = *(const float2*)(p + (size_t)j * IMG_W);
                    const int ilo = (j - (KSZ - 1)) < 0 ? 0 : (j - (KSZ - 1));
                    const int ihi = j < (GRP_ROWS - 1) ? j : (GRP_ROWS - 1);
                    #pragma unroll
                    for (int i = ilo; i <= ihi; ++i) {
                        const float kk = kW[j - i];
                        acc[i].x += kk * wv.x;
                        acc[i].y += kk * wv.y;
                    }
                }
            } else {
                // y-edge: clamp rows
                #pragma unroll
                for (int j = 0; j < VROWS; ++j) {
                    int gy = ybase + j;
                    gy = gy < 0 ? 0 : (gy > IMG_H - 1 ? IMG_H - 1 : gy);
                    const float2 wv = *(const float2*)(src + (size_t)gy * IMG_W + gx);
                    const int ilo = (j - (KSZ - 1)) < 0 ? 0 : (j - (KSZ - 1));
                    const int ihi = j < (GRP_ROWS - 1) ? j : (GRP_ROWS - 1);
                    #pragma unroll
                    for (int i = ilo; i <= ihi; ++i) {
                        const float kk = kW[j - i];
                        acc[i].x += kk * wv.x;
                        acc[i].y += kk * wv.y;
                    }
                }
            }
        } else {
            // x-edge: whole pair clamps to the same edge column (gx always even)
            const int gc = gx < 0 ? 0 : IMG_W - 1;
            #pragma unroll
            for (int j = 0; j < VROWS; ++j) {
                int gy = ybase + j;
                gy = gy < 0 ? 0 : (gy > IMG_H - 1 ? IMG_H - 1 : gy);
                const float v = src[(size_t)gy * IMG_W + gc];
                const int ilo = (j - (KSZ - 1)) < 0 ? 0 : (j - (KSZ - 1));
                const int ihi = j < (GRP_ROWS - 1) ? j : (GRP_ROWS - 1);
                #pragma unroll
                for (int i = ilo; i <= ihi; ++i) {
                    const float kk = kW[j - i];
                    acc[i].x += kk * v;
                    acc[i].y += kk * v;
                }
            }
        }

        #pragma unroll
        for (int i = 0; i < GRP_ROWS; ++i)
            *(float2*)&inter[(g * GRP_ROWS + i) * LDS_STRIDE + ldscol] = acc[i];
    }
    __syncthreads();

    // ---------------- horizontal pass: b128 LDS reads, streaming accumulators
    // 32 rows x 8 chunks x 12 px = 256 threads, all active.
    {
        const int row   = tid >> 3;        // 0..31
        const int chunk = tid & 7;         // 0..7
        const int xl    = chunk * HCHUNK;  // 0,12,..,84 -> 48B steps, 16B aligned

        float acc[HCHUNK];                 // 12 accumulators
        #pragma unroll
        for (int j = 0; j < HCHUNK; ++j) acc[j] = 0.f;

        const float4* lp = (const float4*)&inter[row * LDS_STRIDE + xl];
        #pragma unroll
        for (int m4 = 0; m4 < HREAD / 4; ++m4) {   // 9 x ds_read_b128
            const float4 t = lp[m4];
            #pragma unroll
            for (int e = 0; e < 4; ++e) {
                const int m = 4 * m4 + e;
                const float wv = (e == 0) ? t.x : (e == 1) ? t.y : (e == 2) ? t.z : t.w;
                const int jlo = (m - (KSZ - 1)) < 0 ? 0 : (m - (KSZ - 1));
                const int jhi = m < (HCHUNK - 1) ? m : (HCHUNK - 1);
                #pragma unroll
                for (int j = jlo; j <= jhi; ++j)
                    acc[j] += kW[m - j] * wv;
            }
        }

        const size_t rowbase = (size_t)(y0 + row) * IMG_W;
        const int gx0 = x0 + xl;
        #pragma unroll
        for (int j4 = 0; j4 < HCHUNK / 4; ++j4) {
            float4 o;
            o.x = acc[4 * j4 + 0]; o.y = acc[4 * j4 + 1];
            o.z = acc[4 * j4 + 2]; o.w = acc[4 * j4 + 3];
            const int gx = gx0 + 4 * j4;            // multiple of 4
            if (gx < IMG_W)
                *(float4*)&dst[rowbase + gx] = o;
        }
    }
}

extern "C" void kernel_launch(void* const* d_in, const int* in_sizes, int n_in,
                              void* d_out, int out_size, void* d_ws, size_t ws_size,
                              hipStream_t stream)
{
    const float* img = (const float*)d_in[0];
    float* out = (float*)d_out;

    dim3 grid((IMG_W + TILE_W - 1) / TILE_W,  // 43
              IMG_H / TILE_H,                 // 128
              N_CH);                          // 3
    dim3 block(256);
    gauss_blur_fused<<<grid, block, 0, stream>>>(img, out);
}